// Round 5
// baseline (141.308 us; speedup 1.0000x reference)
//
#include <hip/hip_runtime.h>

#define NFEAT 128
#define CAP 16        // per-destination bucket = 16 ints = exactly one 64B line
#define OVF_CAP 8192  // overflow edge list capacity (expected use: ~30 for Pois(6.4))

static_assert(CAP == 16, "aggregate_kernel's lane mapping assumes CAP == 16");

// clang-native 16B vector for nontemporal builtins (HIP float4 is a struct
// type the builtin rejects; this alias has identical layout).
typedef float vfloat4 __attribute__((ext_vector_type(4)));

// ---------------- Direct-binning path ----------------
// ws layout (ints): bucket[B*CAP] (64B-aligned at ws base) | cnt[B] | ovf_cnt[1] | ovf[2*OVF_CAP]

__global__ void zero_kernel(int* __restrict__ p, int n) {
    int t = blockIdx.x * blockDim.x + threadIdx.x;
    if (t < n) p[t] = 0;
}

// One pass over edges, 4 edges per thread via int4 loads: claim a slot in
// dst's bucket, store src id. The 4 atomics per thread are independent
// (MLP=4); bucket rows are single 64B lines resident in L2 during binning.
__global__ void bin_kernel(const int* __restrict__ src, const int* __restrict__ dst,
                           int* __restrict__ cnt, int* __restrict__ ovf_cnt,
                           int* __restrict__ ovf, int* __restrict__ bucket,
                           int E, int B) {
    int t = blockIdx.x * blockDim.x + threadIdx.x;
    int e0 = t << 2;
    if (e0 >= E) return;
    if (e0 + 4 <= E) {
        const int4 d4 = *(const int4*)(dst + e0);
        const int4 s4 = *(const int4*)(src + e0);
        int dd[4] = {d4.x, d4.y, d4.z, d4.w};
        int ss[4] = {s4.x, s4.y, s4.z, s4.w};
        #pragma unroll
        for (int i = 0; i < 4; ++i) {
            int d = dd[i];
            if (d >= B) continue;
            int pos = atomicAdd(&cnt[d], 1);
            if (pos < CAP) {
                bucket[d * CAP + pos] = ss[i];
            } else {
                int o = atomicAdd(ovf_cnt, 1);
                if (o < OVF_CAP) { ovf[2 * o] = ss[i]; ovf[2 * o + 1] = d; }
            }
        }
    } else {
        for (int e = e0; e < E; ++e) {
            int d = dst[e];
            if (d >= B) continue;
            int pos = atomicAdd(&cnt[d], 1);
            if (pos < CAP) {
                bucket[d * CAP + pos] = src[e];
            } else {
                int o = atomicAdd(ovf_cnt, 1);
                if (o < OVF_CAP) { ovf[2 * o] = src[e]; ovf[2 * o + 1] = d; }
            }
        }
    }
}

// FOUR destination rows per wave: quarter-wave (16 lanes) per row, lane owns
// 2 float4s (32B -> 512B row access from 16 lanes). Bucket slots for all 4
// rows load as ONE fully-coalesced 256B wave read (CAP==16: lane = h*16+l
// maps exactly to bucket[w0*16 + lane]). Four independent gather chains per
// wave, each unrolled x4 -> 16 outstanding row-gathers/wave, to test the
// request-rate-bound hypothesis. Rows that overflowed CAP scan the tiny ovf
// list inline. Nontemporal: bucket is read-once (don't displace x in L2);
// out is write-once.
__global__ void aggregate_kernel(const float4* __restrict__ x4,
                                 const int* __restrict__ cnt,
                                 const int* __restrict__ ovf_cnt,
                                 const int* __restrict__ ovf,
                                 const int* __restrict__ bucket,
                                 float4* __restrict__ out4, int B) {
    int wv   = (blockIdx.x * blockDim.x + threadIdx.x) >> 6;  // wave id = row quad
    int lane = threadIdx.x & 63;
    int h    = lane >> 4;          // which row of the quad this quarter owns
    int l    = lane & 15;          // float4-pair column within the row
    int w0   = wv * 4;
    if (w0 >= B) return;
    int row   = w0 + h;
    bool rowok = row < B;          // B % 4 == 0 in practice; guard anyway

    int korig = rowok ? cnt[row] : 0;
    int k = korig > CAP ? CAP : korig;
    // bucket[(w0+h)*16 + l] == bucket[w0*16 + lane]: one 256B wave load.
    int sid = (l < k) ? __builtin_nontemporal_load(&bucket[(size_t)w0 * CAP + lane]) : 0;

    size_t xrow = (size_t)row * 32;
    float4 xd0 = rowok ? x4[xrow + 2 * l]     : make_float4(0.f, 0.f, 0.f, 0.f);
    float4 xd1 = rowok ? x4[xrow + 2 * l + 1] : make_float4(0.f, 0.f, 0.f, 0.f);

    // kmax over the 4 quarters of this wave
    int kq = k, tt;
    tt = __shfl(kq, lane ^ 16, 64); kq = kq > tt ? kq : tt;
    tt = __shfl(kq, lane ^ 32, 64); kq = kq > tt ? kq : tt;
    int kmax = kq;

    float4 a0 = make_float4(0.f, 0.f, 0.f, 0.f);
    float4 a1 = make_float4(0.f, 0.f, 0.f, 0.f);
    int hb = h << 4;
    int j = 0;
    for (; j + 4 <= kmax; j += 4) {
        int s0 = __shfl(sid, hb + j,     64);
        int s1 = __shfl(sid, hb + j + 1, 64);
        int s2 = __shfl(sid, hb + j + 2, 64);
        int s3 = __shfl(sid, hb + j + 3, 64);
        float4 v00 = x4[(size_t)s0 * 32 + 2 * l], v01 = x4[(size_t)s0 * 32 + 2 * l + 1];
        float4 v10 = x4[(size_t)s1 * 32 + 2 * l], v11 = x4[(size_t)s1 * 32 + 2 * l + 1];
        float4 v20 = x4[(size_t)s2 * 32 + 2 * l], v21 = x4[(size_t)s2 * 32 + 2 * l + 1];
        float4 v30 = x4[(size_t)s3 * 32 + 2 * l], v31 = x4[(size_t)s3 * 32 + 2 * l + 1];
        if (j + 1 <= k) { a0.x += v00.x; a0.y += v00.y; a0.z += v00.z; a0.w += v00.w;
                          a1.x += v01.x; a1.y += v01.y; a1.z += v01.z; a1.w += v01.w; }
        if (j + 2 <= k) { a0.x += v10.x; a0.y += v10.y; a0.z += v10.z; a0.w += v10.w;
                          a1.x += v11.x; a1.y += v11.y; a1.z += v11.z; a1.w += v11.w; }
        if (j + 3 <= k) { a0.x += v20.x; a0.y += v20.y; a0.z += v20.z; a0.w += v20.w;
                          a1.x += v21.x; a1.y += v21.y; a1.z += v21.z; a1.w += v21.w; }
        if (j + 4 <= k) { a0.x += v30.x; a0.y += v30.y; a0.z += v30.z; a0.w += v30.w;
                          a1.x += v31.x; a1.y += v31.y; a1.z += v31.z; a1.w += v31.w; }
    }
    for (; j < kmax; ++j) {
        int s = __shfl(sid, hb + j, 64);
        float4 v0 = x4[(size_t)s * 32 + 2 * l], v1 = x4[(size_t)s * 32 + 2 * l + 1];
        if (j < k) { a0.x += v0.x; a0.y += v0.y; a0.z += v0.z; a0.w += v0.w;
                     a1.x += v1.x; a1.y += v1.y; a1.z += v1.z; a1.w += v1.w; }
    }

    if (korig > CAP) {  // rare: finish this row from the overflow list
        int novf = *ovf_cnt;
        if (novf > OVF_CAP) novf = OVF_CAP;
        for (int o = 0; o < novf; ++o) {
            if (ovf[2 * o + 1] == row) {
                int s = ovf[2 * o];
                float4 v0 = x4[(size_t)s * 32 + 2 * l], v1 = x4[(size_t)s * 32 + 2 * l + 1];
                a0.x += v0.x; a0.y += v0.y; a0.z += v0.z; a0.w += v0.w;
                a1.x += v1.x; a1.y += v1.y; a1.z += v1.z; a1.w += v1.w;
            }
        }
    }

    if (rowok) {
        size_t o = (size_t)row * 64;               // out row = 256 floats = 64 float4
        vfloat4 x0n = {xd0.x, xd0.y, xd0.z, xd0.w};
        vfloat4 x1n = {xd1.x, xd1.y, xd1.z, xd1.w};
        vfloat4 a0n = {a0.x, a0.y, a0.z, a0.w};
        vfloat4 a1n = {a1.x, a1.y, a1.z, a1.w};
        __builtin_nontemporal_store(x0n, (vfloat4*)&out4[o + 2 * l]);          // left: x[row]
        __builtin_nontemporal_store(x1n, (vfloat4*)&out4[o + 2 * l + 1]);
        __builtin_nontemporal_store(a0n, (vfloat4*)&out4[o + 32 + 2 * l]);     // right: sum
        __builtin_nontemporal_store(a1n, (vfloat4*)&out4[o + 32 + 2 * l + 1]);
    }
}

// ---------------- Fallback: R1 CSR path (passed) ----------------
__global__ void hist_kernel(const int* __restrict__ dst, int* __restrict__ cnt,
                            int E, int B) {
    int e = blockIdx.x * blockDim.x + threadIdx.x;
    if (e >= E) return;
    int d = dst[e];
    if (d < B) atomicAdd(&cnt[d], 1);
}

__global__ void alloc_kernel(const int* __restrict__ cnt, int* __restrict__ off,
                             int* __restrict__ deg, int* __restrict__ cursor, int B) {
    int t = blockIdx.x * blockDim.x + threadIdx.x;
    int lane = threadIdx.x & 63;
    int c = (t < B) ? cnt[t] : 0;
    int v = c;
    #pragma unroll
    for (int d = 1; d < 64; d <<= 1) {
        int n = __shfl_up(v, d, 64);
        if (lane >= d) v += n;
    }
    int total = __shfl(v, 63, 64);
    int base = 0;
    if (lane == 63 && total > 0) base = atomicAdd(cursor, total);
    base = __shfl(base, 63, 64);
    if (t < B) { off[t] = base + v - c; deg[t] = c; }
}

__global__ void scatter_kernel(const int* __restrict__ src, const int* __restrict__ dst,
                               int* __restrict__ cnt, const int* __restrict__ off,
                               int* __restrict__ bucket, int E, int B) {
    int e = blockIdx.x * blockDim.x + threadIdx.x;
    if (e >= E) return;
    int d = dst[e];
    if (d >= B) return;
    int old = atomicSub(&cnt[d], 1);
    bucket[off[d] + old - 1] = src[e];
}

__global__ void aggregate_csr_kernel(const float2* __restrict__ x2,
                                     const int* __restrict__ off, const int* __restrict__ deg,
                                     const int* __restrict__ bucket,
                                     float2* __restrict__ out2, int B) {
    int w = (blockIdx.x * blockDim.x + threadIdx.x) >> 6;
    int lane = threadIdx.x & 63;
    if (w >= B) return;
    int base = off[w];
    int k = deg[w];
    float2 acc = make_float2(0.f, 0.f);
    for (int j = 0; j < k; ++j) {
        int s = bucket[base + j];
        float2 v = x2[(size_t)s * 64 + lane];
        acc.x += v.x; acc.y += v.y;
    }
    float2 xd = x2[(size_t)w * 64 + lane];
    size_t o = (size_t)w * 128;
    out2[o + lane] = xd;
    out2[o + 64 + lane] = acc;
}

extern "C" void kernel_launch(void* const* d_in, const int* in_sizes, int n_in,
                              void* d_out, int out_size, void* d_ws, size_t ws_size,
                              hipStream_t stream) {
    const float* x  = (const float*)d_in[0];
    const int*   ei = (const int*)d_in[1];
    const int E = in_sizes[1] / 2;
    const int B = out_size / (2 * NFEAT);
    float* out = (float*)d_out;
    const int* src = ei;
    const int* dst = ei + E;

    size_t need_bin = ((size_t)B * (CAP + 1) + 1 + 2 * OVF_CAP) * sizeof(int);

    if (ws_size >= need_bin) {
        // bucket first so each 16-int row is one aligned 64B line.
        int* bucket  = (int*)d_ws;
        int* cnt     = bucket + (size_t)B * CAP;
        int* ovf_cnt = cnt + B;
        int* ovf     = ovf_cnt + 1;

        int nz = B + 1;
        zero_kernel<<<(nz + 255) / 256, 256, 0, stream>>>(cnt, nz);
        int nbin_threads = (E + 3) / 4;
        bin_kernel<<<(nbin_threads + 255) / 256, 256, 0, stream>>>(
            src, dst, cnt, ovf_cnt, ovf, bucket, E, B);
        int nquads = (B + 3) / 4;                  // one wave per row quad
        aggregate_kernel<<<(nquads + 3) / 4, 256, 0, stream>>>(
            (const float4*)x, cnt, ovf_cnt, ovf, bucket, (float4*)out, B);
    } else {
        int* cnt    = (int*)d_ws;
        int* off    = cnt + B;
        int* deg    = off + B;
        int* cursor = deg + B;
        int* bucket = cursor + 1;
        int nz = 3 * B + 1;
        zero_kernel<<<(nz + 255) / 256, 256, 0, stream>>>(cnt, nz);
        hist_kernel<<<(E + 255) / 256, 256, 0, stream>>>(dst, cnt, E, B);
        alloc_kernel<<<(B + 255) / 256, 256, 0, stream>>>(cnt, off, deg, cursor, B);
        scatter_kernel<<<(E + 255) / 256, 256, 0, stream>>>(src, dst, cnt, off, bucket, E, B);
        aggregate_csr_kernel<<<(B + 3) / 4, 256, 0, stream>>>(
            (const float2*)x, off, deg, bucket, (float2*)out, B);
    }
}